// Round 11
// baseline (501.030 us; speedup 1.0000x reference)
//
#include <hip/hip_runtime.h>
#include <hip/hip_fp16.h>
#include <hip/hip_cooperative_groups.h>
#include <math.h>

namespace cg = cooperative_groups;

#define N_NODES 10000
#define N_EDGES 160000
#define N_TOT   170000   // edges + self loops
#define NAG     5000
#define HC      1024     // H*C_HID
#define CH      128
#define NEG     0.2f

typedef _Float16 f16x8 __attribute__((ext_vector_type(8)));
typedef _Float16 f16x2 __attribute__((ext_vector_type(2)));
typedef float f32x4 __attribute__((ext_vector_type(4)));

// ======================= shared device helpers =======================
__device__ __forceinline__ __half2 pk_max(__half2 a, __half2 b) {
    __half2 r;
    asm volatile("v_pk_max_f16 %0, %1, %2" : "=v"(r) : "v"(a), "v"(b));
    return r;
}

__device__ __forceinline__ void edge_accum(float4 raw, const __half2* xr2, const __half2* att2,
                                           float& lsum, float* acc, bool valid) {
    __half2* hp = (__half2*)&raw;
    const __half2 neg2 = __float2half2_rn(NEG);
    float p = 0.f;
    #pragma unroll
    for (int j = 0; j < 4; j++) {
        __half2 z = __hadd2(hp[j], xr2[j]);
        __half2 lz = pk_max(z, __hmul2(z, neg2));
#if __has_builtin(__builtin_amdgcn_fdot2)
        p = __builtin_amdgcn_fdot2(*(f16x2*)&lz, *(const f16x2*)&att2[j], p, false);
#else
        float2 lf = __half22float2(lz);
        float2 af = __half22float2(att2[j]);
        p = fmaf(lf.x, af.x, p);
        p = fmaf(lf.y, af.y, p);
#endif
    }
    p += __shfl_xor(p, 1, 64);
    p += __shfl_xor(p, 2, 64);
    p += __shfl_xor(p, 4, 64);
    p += __shfl_xor(p, 8, 64);
    float w = valid ? __expf(p) : 0.f;
    lsum += w;
    #pragma unroll
    for (int j = 0; j < 4; j++) {
        acc[2 * j]     = fmaf(__low2float(hp[j]),  w, acc[2 * j]);
        acc[2 * j + 1] = fmaf(__high2float(hp[j]), w, acc[2 * j + 1]);
    }
}

// ---- MFMA GEMM phase (grid-stride over virtual tiles). eps overlays ash. ----
template <int K, int KA>
__device__ void gemm_phase(char* smem,
                           const float* __restrict__ A,
                           const _Float16* __restrict__ Whl, const float* __restrict__ bl,
                           const _Float16* __restrict__ Whr, const float* __restrict__ br,
                           _Float16* __restrict__ xl, float* __restrict__ xr,
                           int limitL, int limitR) {
    _Float16* ash = (_Float16*)smem;
    float (*eps)[68] = (float(*)[68])smem;
    const int AS = K + 8;
    int t = threadIdx.x;
    int w = t >> 6, l = t & 63;
    int m = l & 15, q = l >> 4;
    const int ntiles = ((N_NODES + 63) / 64) * 8;

    for (int vt = blockIdx.x; vt < ntiles; vt += gridDim.x) {
        int by = vt & 7;
        int rowblk = (vt >> 3) * 64;
        bool right = by >= 4;
        if (rowblk >= (right ? limitR : limitL)) continue;
        const _Float16* Wh = right ? Whr : Whl;
        const float* bs    = right ? br : bl;
        int colbase = (by & 3) * 256;

        __syncthreads();   // prior iteration's eps reads done before restaging ash
        for (int idx = t; idx < 64 * (K / 8); idx += 256) {
            int r  = idx / (K / 8);
            int c8 = (idx % (K / 8)) * 8;
            int row = rowblk + r;
            float4 v0 = make_float4(0.f, 0.f, 0.f, 0.f);
            float4 v1 = make_float4(0.f, 0.f, 0.f, 0.f);
            if (row < N_NODES && c8 < KA) {
                v0 = *(const float4*)(A + (size_t)row * KA + c8);
                v1 = *(const float4*)(A + (size_t)row * KA + c8 + 4);
            }
            f16x8 hv;
            hv[0] = (_Float16)v0.x; hv[1] = (_Float16)v0.y; hv[2] = (_Float16)v0.z; hv[3] = (_Float16)v0.w;
            hv[4] = (_Float16)v1.x; hv[5] = (_Float16)v1.y; hv[6] = (_Float16)v1.z; hv[7] = (_Float16)v1.w;
            *(f16x8*)&ash[r * AS + c8] = hv;
        }
        __syncthreads();

        f32x4 acc[16];
        #pragma unroll
        for (int i = 0; i < 16; i++) acc[i] = (f32x4){0.f, 0.f, 0.f, 0.f};

        for (int k0 = 0; k0 < K; k0 += 32) {
            f16x8 af = *(const f16x8*)&ash[(w * 16 + m) * AS + k0 + q * 8];
            const _Float16* wp = Wh + (size_t)(colbase + m) * K + k0 + q * 8;
            #pragma unroll
            for (int tile = 0; tile < 16; tile++) {
                f16x8 bf = *(const f16x8*)(wp + (size_t)tile * 16 * K);
                acc[tile] = __builtin_amdgcn_mfma_f32_16x16x32_f16(af, bf, acc[tile], 0, 0, 0);
            }
        }

        float bv[16];
        #pragma unroll
        for (int tile = 0; tile < 16; tile++) bv[tile] = bs[colbase + tile * 16 + m];

        for (int cgk = 0; cgk < 4; cgk++) {
            __syncthreads();
            #pragma unroll
            for (int tt = 0; tt < 4; tt++) {
                int tile = cgk * 4 + tt;
                int cl = tt * 16 + m;
                #pragma unroll
                for (int reg = 0; reg < 4; reg++)
                    eps[w * 16 + q * 4 + reg][cl] = acc[tile][reg] + bv[tile];
            }
            __syncthreads();
            int colg = colbase + cgk * 64;
            int cc = (t & 15) * 4;
            #pragma unroll
            for (int it = 0; it < 4; it++) {
                int r = it * 16 + (t >> 4);
                int row = rowblk + r;
                if (row < N_NODES) {
                    float4 v = *(const float4*)&eps[r][cc];
                    if (right) {
                        *(float4*)(xr + (size_t)row * HC + colg + cc) = v;
                    } else {
                        __half2 h01 = __floats2half2_rn(v.x, v.y);
                        __half2 h23 = __floats2half2_rn(v.z, v.w);
                        float2 st;
                        st.x = *(float*)&h01;
                        st.y = *(float*)&h23;
                        *(float2*)(xl + (size_t)row * HC + colg + cc) = st;
                    }
                }
            }
        }
    }
}

// ---- GATv2 phase (grid-stride over dst nodes) ----
template <int LAYER>
__device__ void gat_phase(char* smem, int ndst,
                          const __half* __restrict__ xl, const float* __restrict__ xr,
                          const float* __restrict__ att, const float* __restrict__ bias,
                          const int* __restrict__ row_ptr, const int* __restrict__ srcs,
                          float* __restrict__ h_out,
                          const float* __restrict__ Wlin, const float* __restrict__ blin,
                          float* __restrict__ out) {
    float* part  = (float*)smem;            // [2][HC]
    float* lpart = (float*)(smem + 8192);   // [2][8]
    float* hrow  = (float*)(smem + 8256);   // [CH]
    int t = threadIdx.x;
    int slot = t >> 7;
    int c0 = (t & 127) * 8;

    for (int dstn = blockIdx.x; dstn < ndst; dstn += gridDim.x) {
        __half2 xr2[4], att2[4];
        {
            float4 a0 = *(const float4*)(xr + (size_t)dstn * HC + c0);
            float4 a1 = *(const float4*)(xr + (size_t)dstn * HC + c0 + 4);
            xr2[0] = __floats2half2_rn(a0.x, a0.y);
            xr2[1] = __floats2half2_rn(a0.z, a0.w);
            xr2[2] = __floats2half2_rn(a1.x, a1.y);
            xr2[3] = __floats2half2_rn(a1.z, a1.w);
            float4 b0 = *(const float4*)(att + c0);
            float4 b1 = *(const float4*)(att + c0 + 4);
            att2[0] = __floats2half2_rn(b0.x, b0.y);
            att2[1] = __floats2half2_rn(b0.z, b0.w);
            att2[2] = __floats2half2_rn(b1.x, b1.y);
            att2[3] = __floats2half2_rn(b1.z, b1.w);
        }

        float acc[8];
        #pragma unroll
        for (int j = 0; j < 8; j++) acc[j] = 0.f;
        float lsum = 0.f;

        int e0 = row_ptr[dstn], e1 = row_ptr[dstn + 1];
        int e = e0;
        for (; e + 16 <= e1; e += 16) {
            int s[8];
            #pragma unroll
            for (int i = 0; i < 8; i++) s[i] = srcs[e + slot + 2 * i];
            float4 raw[8];
            #pragma unroll
            for (int i = 0; i < 8; i++) raw[i] = *(const float4*)(xl + (size_t)s[i] * HC + c0);
            #pragma unroll
            for (int i = 0; i < 8; i++) edge_accum(raw[i], xr2, att2, lsum, acc, true);
        }
        for (; e + 4 <= e1; e += 4) {
            int s[2];
            #pragma unroll
            for (int i = 0; i < 2; i++) s[i] = srcs[e + slot + 2 * i];
            float4 raw[2];
            #pragma unroll
            for (int i = 0; i < 2; i++) raw[i] = *(const float4*)(xl + (size_t)s[i] * HC + c0);
            #pragma unroll
            for (int i = 0; i < 2; i++) edge_accum(raw[i], xr2, att2, lsum, acc, true);
        }
        for (; e < e1; e += 2) {
            int ee = e + slot;
            bool valid = ee < e1;
            int s = srcs[valid ? ee : e];
            float4 raw = *(const float4*)(xl + (size_t)s * HC + c0);
            edge_accum(raw, xr2, att2, lsum, acc, valid);
        }

        #pragma unroll
        for (int j = 0; j < 8; j++) part[slot * HC + c0 + j] = acc[j];
        if ((t & 15) == 0) lpart[slot * 8 + (c0 >> 7)] = lsum;
        __syncthreads();

        if (t < 128) {
            int head = t >> 4;
            float lv = lpart[head] + lpart[8 + head];
            float inv = 1.f / (lv + 1e-16f);
            #pragma unroll
            for (int j = 0; j < 8; j++) {
                int c = t * 8 + j;
                part[c] = (part[c] + part[HC + c]) * inv;
            }
        }
        __syncthreads();
        if (t < 128) {
            float ssum = 0.f;
            #pragma unroll
            for (int h = 0; h < 8; h++) ssum += part[h * 128 + t];
            float val = fmaxf(ssum * 0.125f + bias[t], 0.f);
            if (LAYER == 1) h_out[(size_t)dstn * CH + t] = val;
            else hrow[t] = val;
        }
        if (LAYER == 2) {
            __syncthreads();
            if (t < 64) {
                int j = t & 7, p8 = t >> 3;
                float v = 0.f;
                #pragma unroll
                for (int kk = 0; kk < 16; kk++) {
                    int k = p8 * 16 + kk;
                    v = fmaf(hrow[k], Wlin[k * 8 + j], v);
                }
                v += __shfl_xor(v, 8, 64);
                v += __shfl_xor(v, 16, 64);
                v += __shfl_xor(v, 32, 64);
                if (t < 8) out[(size_t)dstn * 8 + t] = v + blin[t];
            }
        }
        __syncthreads();
    }
}

// ======================= mono cooperative kernel =======================
__global__ __launch_bounds__(256, 4) void mono(
    const float* __restrict__ x, const int* __restrict__ ei,
    const float* __restrict__ Wl1, const float* __restrict__ bl1,
    const float* __restrict__ Wr1, const float* __restrict__ br1,
    const float* __restrict__ att1, const float* __restrict__ b1,
    const float* __restrict__ Wl2, const float* __restrict__ bl2,
    const float* __restrict__ Wr2, const float* __restrict__ br2,
    const float* __restrict__ att2, const float* __restrict__ b2,
    const float* __restrict__ Wlin, const float* __restrict__ blin,
    float* __restrict__ out,
    __half* __restrict__ xlh, float* __restrict__ xr, float* __restrict__ h1,
    _Float16* __restrict__ w1l, _Float16* __restrict__ w1r,
    _Float16* __restrict__ w2l, _Float16* __restrict__ w2r,
    int* __restrict__ deg, int* __restrict__ row_ptr,
    int* __restrict__ cursor, int* __restrict__ srcs) {

    cg::grid_group grid = cg::this_grid();
    __shared__ __align__(16) char smem[17408];
    const int t = threadIdx.x;
    const int gtid = blockIdx.x * 256 + t;
    const int gstr = gridDim.x * 256;
    const int* esrc = ei;
    const int* edst = ei + N_EDGES;

    // Phase A: zero deg + convert weights to fp16 [col][k]
    for (int i = gtid; i < N_NODES; i += gstr) deg[i] = 0;
    {
        const int S1 = 1024 * 32, S2 = 1024 * 128;
        for (int gid = gtid; gid < 2 * S1 + 2 * S2; gid += gstr) {
            if (gid < 2 * S1) {
                const float* W = (gid < S1) ? Wl1 : Wr1;
                _Float16* o    = (gid < S1) ? w1l : w1r;
                int g = (gid < S1) ? gid : gid - S1;
                int col = g & 1023, k = g >> 10;
                float v = (k < 16) ? W[k * 1024 + col] : 0.f;
                o[col * 32 + k] = (_Float16)v;
            } else {
                int g = gid - 2 * S1;
                const float* W = (g < S2) ? Wl2 : Wr2;
                _Float16* o    = (g < S2) ? w2l : w2r;
                int gg = (g < S2) ? g : g - S2;
                int col = gg & 1023, k = gg >> 10;
                o[col * 128 + k] = (_Float16)W[k * 1024 + col];
            }
        }
    }
    grid.sync();

    // Phase B: degree histogram
    for (int e = gtid; e < N_EDGES; e += gstr) atomicAdd(&deg[edst[e]], 1);
    grid.sync();

    // Phase C: prefix scan (block 0)
    if (blockIdx.x == 0) {
        int* sp = (int*)smem;
        int base = t * 40;
        int sum = 0;
        for (int i = 0; i < 40; i++) {
            int idx = base + i;
            if (idx < N_NODES) sum += deg[idx] + 1;   // +1 self loop
        }
        sp[t] = sum;
        __syncthreads();
        for (int off = 1; off < 256; off <<= 1) {
            int v = (t >= off) ? sp[t - off] : 0;
            __syncthreads();
            sp[t] += v;
            __syncthreads();
        }
        int run = (t > 0) ? sp[t - 1] : 0;
        for (int i = 0; i < 40; i++) {
            int idx = base + i;
            if (idx < N_NODES) {
                row_ptr[idx] = run;
                cursor[idx] = run;
                run += deg[idx] + 1;
            }
        }
        if (t == 255) row_ptr[N_NODES] = sp[255];
    }
    grid.sync();

    // Phase D: scatter CSR + layer-1 GEMM (independent work)
    for (int e = gtid; e < N_TOT; e += gstr) {
        if (e < N_EDGES) {
            int p = atomicAdd(&cursor[edst[e]], 1);
            srcs[p] = esrc[e];
        } else {
            int i = e - N_EDGES;
            int p = atomicAdd(&cursor[i], 1);
            srcs[p] = i;
        }
    }
    gemm_phase<32, 16>(smem, x, w1l, bl1, w1r, br1, (_Float16*)xlh, xr, N_NODES, N_NODES);
    grid.sync();

    // Phase E: layer-1 GAT
    gat_phase<1>(smem, N_NODES, xlh, xr, att1, b1, row_ptr, srcs, h1, nullptr, nullptr, nullptr);
    grid.sync();

    // Phase F: layer-2 GEMM (xr only for drone rows)
    gemm_phase<128, 128>(smem, h1, w2l, bl2, w2r, br2, (_Float16*)xlh, xr, N_NODES, NAG);
    grid.sync();

    // Phase G: layer-2 GAT + final linear (drones only)
    gat_phase<2>(smem, NAG, xlh, xr, att2, b2, row_ptr, srcs, nullptr, Wlin, blin, out);
}

// ======================= fallback discrete kernels (R9, known-good) =======================
__global__ __launch_bounds__(256) void hist_kernel(const int* __restrict__ dst,
                                                   int* __restrict__ deg) {
    int e = blockIdx.x * 256 + threadIdx.x;
    if (e < N_EDGES) atomicAdd(&deg[dst[e]], 1);
}

__global__ __launch_bounds__(1024) void scan_kernel(const int* __restrict__ deg,
                                                    int* __restrict__ row_ptr,
                                                    int* __restrict__ cursor) {
    int t = threadIdx.x;
    const int CHK = 10;
    int base = t * CHK;
    int loc[CHK];
    int sum = 0;
    #pragma unroll
    for (int i = 0; i < CHK; i++) {
        int idx = base + i;
        int d = (idx < N_NODES) ? (deg[idx] + 1) : 0;
        loc[i] = sum;
        sum += d;
    }
    __shared__ int part[1024];
    part[t] = sum;
    __syncthreads();
    for (int off = 1; off < 1024; off <<= 1) {
        int v = (t >= off) ? part[t - off] : 0;
        __syncthreads();
        part[t] += v;
        __syncthreads();
    }
    int pre = (t > 0) ? part[t - 1] : 0;
    #pragma unroll
    for (int i = 0; i < CHK; i++) {
        int idx = base + i;
        if (idx < N_NODES) {
            int v = pre + loc[i];
            row_ptr[idx] = v;
            cursor[idx] = v;
        }
    }
    if (t == 1023) row_ptr[N_NODES] = part[1023];
}

__global__ __launch_bounds__(256) void scatter_kernel(const int* __restrict__ src,
                                                      const int* __restrict__ dst,
                                                      int* __restrict__ cursor,
                                                      int* __restrict__ srcs) {
    int e = blockIdx.x * 256 + threadIdx.x;
    if (e < N_EDGES) {
        int p = atomicAdd(&cursor[dst[e]], 1);
        srcs[p] = src[e];
    } else if (e < N_TOT) {
        int i = e - N_EDGES;
        int p = atomicAdd(&cursor[i], 1);
        srcs[p] = i;
    }
}

__global__ __launch_bounds__(256) void convert_w(const float* __restrict__ Wl1, const float* __restrict__ Wr1,
                                                 const float* __restrict__ Wl2, const float* __restrict__ Wr2,
                                                 _Float16* __restrict__ w1l, _Float16* __restrict__ w1r,
                                                 _Float16* __restrict__ w2l, _Float16* __restrict__ w2r) {
    int gid = blockIdx.x * 256 + threadIdx.x;
    const int S1 = 1024 * 32, S2 = 1024 * 128;
    if (gid < 2 * S1) {
        const float* W = (gid < S1) ? Wl1 : Wr1;
        _Float16* o    = (gid < S1) ? w1l : w1r;
        int g = (gid < S1) ? gid : gid - S1;
        int col = g & 1023, k = g >> 10;
        float v = (k < 16) ? W[k * 1024 + col] : 0.f;
        o[col * 32 + k] = (_Float16)v;
    } else {
        int g = gid - 2 * S1;
        if (g >= 2 * S2) return;
        const float* W = (g < S2) ? Wl2 : Wr2;
        _Float16* o    = (g < S2) ? w2l : w2r;
        int gg = (g < S2) ? g : g - S2;
        int col = gg & 1023, k = gg >> 10;
        o[col * 128 + k] = (_Float16)W[k * 1024 + col];
    }
}

template <int K, int KA>
__global__ __launch_bounds__(256) void gemm_mfma(const float* __restrict__ A,
                                                 const _Float16* __restrict__ Whl, const float* __restrict__ bl,
                                                 const _Float16* __restrict__ Whr, const float* __restrict__ br,
                                                 _Float16* __restrict__ xl, float* __restrict__ xr,
                                                 int limitL, int limitR) {
    __shared__ __align__(16) char smem[17408];
    // single-tile wrapper over gemm_phase logic
    _Float16* ash = (_Float16*)smem;
    float (*eps)[68] = (float(*)[68])smem;
    const int AS = K + 8;
    int rowblk = blockIdx.x * 64;
    bool right = blockIdx.y >= 4;
    if (rowblk >= (right ? limitR : limitL)) return;
    const _Float16* Wh = right ? Whr : Whl;
    const float* bs    = right ? br : bl;
    int colbase = (blockIdx.y & 3) * 256;
    int t = threadIdx.x;
    int w = t >> 6, l = t & 63;
    int m = l & 15, q = l >> 4;

    for (int idx = t; idx < 64 * (K / 8); idx += 256) {
        int r  = idx / (K / 8);
        int c8 = (idx % (K / 8)) * 8;
        int row = rowblk + r;
        float4 v0 = make_float4(0.f, 0.f, 0.f, 0.f);
        float4 v1 = make_float4(0.f, 0.f, 0.f, 0.f);
        if (row < N_NODES && c8 < KA) {
            v0 = *(const float4*)(A + (size_t)row * KA + c8);
            v1 = *(const float4*)(A + (size_t)row * KA + c8 + 4);
        }
        f16x8 hv;
        hv[0] = (_Float16)v0.x; hv[1] = (_Float16)v0.y; hv[2] = (_Float16)v0.z; hv[3] = (_Float16)v0.w;
        hv[4] = (_Float16)v1.x; hv[5] = (_Float16)v1.y; hv[6] = (_Float16)v1.z; hv[7] = (_Float16)v1.w;
        *(f16x8*)&ash[r * AS + c8] = hv;
    }
    __syncthreads();

    f32x4 acc[16];
    #pragma unroll
    for (int i = 0; i < 16; i++) acc[i] = (f32x4){0.f, 0.f, 0.f, 0.f};

    for (int k0 = 0; k0 < K; k0 += 32) {
        f16x8 af = *(const f16x8*)&ash[(w * 16 + m) * AS + k0 + q * 8];
        const _Float16* wp = Wh + (size_t)(colbase + m) * K + k0 + q * 8;
        #pragma unroll
        for (int tile = 0; tile < 16; tile++) {
            f16x8 bf = *(const f16x8*)(wp + (size_t)tile * 16 * K);
            acc[tile] = __builtin_amdgcn_mfma_f32_16x16x32_f16(af, bf, acc[tile], 0, 0, 0);
        }
    }

    float bv[16];
    #pragma unroll
    for (int tile = 0; tile < 16; tile++) bv[tile] = bs[colbase + tile * 16 + m];

    for (int cgk = 0; cgk < 4; cgk++) {
        __syncthreads();
        #pragma unroll
        for (int tt = 0; tt < 4; tt++) {
            int tile = cgk * 4 + tt;
            int cl = tt * 16 + m;
            #pragma unroll
            for (int reg = 0; reg < 4; reg++)
                eps[w * 16 + q * 4 + reg][cl] = acc[tile][reg] + bv[tile];
        }
        __syncthreads();
        int colg = colbase + cgk * 64;
        int cc = (t & 15) * 4;
        #pragma unroll
        for (int it = 0; it < 4; it++) {
            int r = it * 16 + (t >> 4);
            int row = rowblk + r;
            if (row < N_NODES) {
                float4 v = *(const float4*)&eps[r][cc];
                if (right) {
                    *(float4*)(xr + (size_t)row * HC + colg + cc) = v;
                } else {
                    __half2 h01 = __floats2half2_rn(v.x, v.y);
                    __half2 h23 = __floats2half2_rn(v.z, v.w);
                    float2 st;
                    st.x = *(float*)&h01;
                    st.y = *(float*)&h23;
                    *(float2*)(xl + (size_t)row * HC + colg + cc) = st;
                }
            }
        }
    }
}

template <int LAYER>
__global__ __launch_bounds__(256) void gat_kernel(const __half* __restrict__ xl,
                                                  const float* __restrict__ xr,
                                                  const float* __restrict__ att,
                                                  const float* __restrict__ bias,
                                                  const int* __restrict__ row_ptr,
                                                  const int* __restrict__ srcs,
                                                  float* __restrict__ h_out,
                                                  const float* __restrict__ Wlin,
                                                  const float* __restrict__ blin,
                                                  float* __restrict__ out,
                                                  int ndst) {
    __shared__ __align__(16) char smem[8768];
    gat_phase<LAYER>(smem, ndst, xl, xr, att, bias, row_ptr, srcs, h_out, Wlin, blin, out);
}

extern "C" void kernel_launch(void* const* d_in, const int* in_sizes, int n_in,
                              void* d_out, int out_size, void* d_ws, size_t ws_size,
                              hipStream_t stream) {
    const float* x    = (const float*)d_in[0];
    const int*   ei   = (const int*)d_in[1];
    const float* Wl1  = (const float*)d_in[2];
    const float* bl1  = (const float*)d_in[3];
    const float* Wr1  = (const float*)d_in[4];
    const float* br1  = (const float*)d_in[5];
    const float* att1 = (const float*)d_in[6];
    const float* b1   = (const float*)d_in[7];
    const float* Wl2  = (const float*)d_in[8];
    const float* bl2  = (const float*)d_in[9];
    const float* Wr2  = (const float*)d_in[10];
    const float* br2  = (const float*)d_in[11];
    const float* att2 = (const float*)d_in[12];
    const float* b2   = (const float*)d_in[13];
    const float* Wlin = (const float*)d_in[14];
    const float* blin = (const float*)d_in[15];
    float* out = (float*)d_out;

    const int* esrc = ei;
    const int* edst = ei + N_EDGES;

    char* p = (char*)d_ws;
    __half* xlh = (__half*)p;                  p += (size_t)N_NODES * HC * sizeof(__half);
    float*  xr  = (float*)p;                   p += (size_t)N_NODES * HC * sizeof(float);
    float*  h1  = (float*)p;                   p += (size_t)N_NODES * CH * sizeof(float);
    _Float16* w1l = (_Float16*)p;              p += 1024 * 32 * sizeof(_Float16);
    _Float16* w1r = (_Float16*)p;              p += 1024 * 32 * sizeof(_Float16);
    _Float16* w2l = (_Float16*)p;              p += 1024 * 128 * sizeof(_Float16);
    _Float16* w2r = (_Float16*)p;              p += 1024 * 128 * sizeof(_Float16);
    int* deg     = (int*)p;
    int* row_ptr = deg + N_NODES;
    int* cursor  = row_ptr + N_NODES + 16;
    int* srcs    = cursor + N_NODES;

    // ---- attempt cooperative mono launch with query-clamped grid ----
    hipError_t err = hipErrorUnknown;
    {
        int dev = 0;
        (void)hipGetDevice(&dev);
        int cus = 0;
        (void)hipDeviceGetAttribute(&cus, hipDeviceAttributeMultiprocessorCount, dev);
        int maxb = 0;
        (void)hipOccupancyMaxActiveBlocksPerMultiprocessor(&maxb, (const void*)mono, 256, 0);
        long total = (long)maxb * (long)cus;
        if (total >= 64) {
            int g = (int)(total > 1280 ? 1280 : total);
            void* args[] = {
                (void*)&x, (void*)&ei,
                (void*)&Wl1, (void*)&bl1, (void*)&Wr1, (void*)&br1, (void*)&att1, (void*)&b1,
                (void*)&Wl2, (void*)&bl2, (void*)&Wr2, (void*)&br2, (void*)&att2, (void*)&b2,
                (void*)&Wlin, (void*)&blin, (void*)&out,
                (void*)&xlh, (void*)&xr, (void*)&h1,
                (void*)&w1l, (void*)&w1r, (void*)&w2l, (void*)&w2r,
                (void*)&deg, (void*)&row_ptr, (void*)&cursor, (void*)&srcs
            };
            err = hipLaunchCooperativeKernel((void*)mono, dim3(g), dim3(256), args, 0, stream);
        }
    }

    // ---- fallback: discrete R9 sequence ----
    if (err != hipSuccess) {
        (void)hipMemsetAsync(deg, 0, N_NODES * sizeof(int), stream);
        hist_kernel<<<(N_EDGES + 255) / 256, 256, 0, stream>>>(edst, deg);
        scan_kernel<<<1, 1024, 0, stream>>>(deg, row_ptr, cursor);
        scatter_kernel<<<(N_TOT + 255) / 256, 256, 0, stream>>>(esrc, edst, cursor, srcs);
        convert_w<<<1280, 256, 0, stream>>>(Wl1, Wr1, Wl2, Wr2, w1l, w1r, w2l, w2r);

        dim3 ggrid((N_NODES + 63) / 64, 8);
        gemm_mfma<32, 16><<<ggrid, 256, 0, stream>>>(x, w1l, bl1, w1r, br1,
                                                     (_Float16*)xlh, xr, N_NODES, N_NODES);
        gat_kernel<1><<<N_NODES, 256, 0, stream>>>(xlh, xr, att1, b1, row_ptr, srcs,
                                                   h1, nullptr, nullptr, nullptr, N_NODES);
        gemm_mfma<128, 128><<<ggrid, 256, 0, stream>>>(h1, w2l, bl2, w2r, br2,
                                                       (_Float16*)xlh, xr, N_NODES, NAG);
        gat_kernel<2><<<NAG, 256, 0, stream>>>(xlh, xr, att2, b2, row_ptr, srcs,
                                               nullptr, Wlin, blin, out, NAG);
    }
}